// Round 1
// baseline (716.726 us; speedup 1.0000x reference)
//
#include <hip/hip_runtime.h>

// Problem constants (from reference):
//   B=8192 rows; slice_input row = 16384 f32; unmatched row = 256 f32;
//   out row = 256 + 64*128 = 8448 f32.
//   Gathered col j -> slice col (j/128)*256 + (j%128).
constexpr int B        = 8192;
constexpr int SLICE_F4 = 16384 / 4;  // 4096 float4 per slice row
constexpr int UN_F4    = 256 / 4;    // 64 float4 per unmatched row
constexpr int OUT_F4   = 8448 / 4;   // 2112 float4 per out row
constexpr int GATH_F4  = 8192 / 4;   // 2048 float4 gathered per row

// --- Kernel A: detect where_input layout (bool/1B vs int32/4B) and expand a
// per-row int mask into workspace. In an int32 buffer of {0,1}, bytes at
// i%4!=0 within the first 8192 bytes are all zero; in a bool buffer ~half are
// nonzero. Both probe reads are in-bounds under either layout.
__global__ __launch_bounds__(256) void detect_expand_kernel(
    const unsigned char* __restrict__ w, int* __restrict__ mask) {
  __shared__ int s_flag;
  const int t = threadIdx.x;
  if (t == 0) s_flag = 0;
  __syncthreads();
  int local = 0;
  for (int i = t; i < B; i += 256) {
    if ((i & 3) != 0 && w[i] != 0) local = 1;
  }
  if (local) s_flag = 1;  // benign same-value race
  __syncthreads();
  if (s_flag != 0) {
    // bool (1 byte/elem) layout
    for (int b = t; b < B; b += 256) mask[b] = (int)w[b];
  } else {
    // int32 layout
    const int* wi = (const int*)w;
    for (int b = t; b < B; b += 256) mask[b] = wi[b];
  }
}

// --- Kernel B: one block per row. Copy unmatched, then either gather 64x128
// chunks from slice_input (row-uniform mask true) or write zeros (mask false,
// skipping the slice_input read entirely -> ~halves FETCH_SIZE).
__global__ __launch_bounds__(256) void fused_slice_where_cat_kernel(
    const int* __restrict__ mask,
    const float4* __restrict__ slice_in,   // B x 4096 float4
    const float4* __restrict__ unmatched,  // B x 64 float4
    float4* __restrict__ out) {            // B x 2112 float4
  const int b = blockIdx.x;
  const int t = threadIdx.x;
  float4* out_row = out + (size_t)b * OUT_F4;
  if (t < UN_F4) out_row[t] = unmatched[(size_t)b * UN_F4 + t];
  float4* og = out_row + UN_F4;
  if (mask[b] != 0) {
    const float4* src = slice_in + (size_t)b * SLICE_F4;
#pragma unroll
    for (int i = 0; i < 8; ++i) {
      const int v = t + i * 256;           // [0, 2048)
      // chunk s = v/32 (32 float4 = 128 floats per chunk), chunk stride 64 f4
      og[v] = src[((v >> 5) << 6) + (v & 31)];
    }
  } else {
    const float4 z = make_float4(0.f, 0.f, 0.f, 0.f);
#pragma unroll
    for (int i = 0; i < 8; ++i) og[t + i * 256] = z;
  }
}

// Fallback if workspace is too small for the mask: assume int32 layout and
// read where_input directly.
__global__ __launch_bounds__(256) void fused_nows_kernel(
    const int* __restrict__ where_in,
    const float4* __restrict__ slice_in,
    const float4* __restrict__ unmatched,
    float4* __restrict__ out) {
  const int b = blockIdx.x;
  const int t = threadIdx.x;
  float4* out_row = out + (size_t)b * OUT_F4;
  if (t < UN_F4) out_row[t] = unmatched[(size_t)b * UN_F4 + t];
  float4* og = out_row + UN_F4;
  if (where_in[b] != 0) {
    const float4* src = slice_in + (size_t)b * SLICE_F4;
#pragma unroll
    for (int i = 0; i < 8; ++i) {
      const int v = t + i * 256;
      og[v] = src[((v >> 5) << 6) + (v & 31)];
    }
  } else {
    const float4 z = make_float4(0.f, 0.f, 0.f, 0.f);
#pragma unroll
    for (int i = 0; i < 8; ++i) og[t + i * 256] = z;
  }
}

extern "C" void kernel_launch(void* const* d_in, const int* in_sizes, int n_in,
                              void* d_out, int out_size, void* d_ws, size_t ws_size,
                              hipStream_t stream) {
  // setup_inputs order: where_input (B), slice_input (B*16384), unmatched
  // (B*256), cat_dim (1), slice_dim (1). Output: B*8448 f32.
  const unsigned char* d_where = (const unsigned char*)d_in[0];
  const float4* d_slice = (const float4*)d_in[1];
  const float4* d_un    = (const float4*)d_in[2];
  float4* out = (float4*)d_out;

  if (ws_size >= (size_t)B * sizeof(int)) {
    int* d_mask = (int*)d_ws;
    detect_expand_kernel<<<1, 256, 0, stream>>>(d_where, d_mask);
    fused_slice_where_cat_kernel<<<B, 256, 0, stream>>>(d_mask, d_slice, d_un, out);
  } else {
    fused_nows_kernel<<<B, 256, 0, stream>>>((const int*)d_in[0], d_slice, d_un, out);
  }
}

// Round 3
// 692.262 us; speedup vs baseline: 1.0353x; 1.0353x over previous
//
#include <hip/hip_runtime.h>

// Problem shape (from reference):
//   B=8192 rows; slice_input row = 16384 f32; unmatched row = 256 f32;
//   out row = 256 + 64*128 = 8448 f32.
//   Gathered col j -> slice col (j/128)*256 + (j%128).
//   Row masked off (where_input[b]==0) -> gathered part is zeros.
constexpr int B        = 8192;
constexpr int SLICE_F4 = 16384 / 4;  // 4096 float4 per slice row
constexpr int UN_F4    = 256 / 4;    // 64 float4 per unmatched row
constexpr int OUT_F4   = 8448 / 4;   // 2112 float4 per out row

// Native clang vector type: __builtin_nontemporal_* accepts vectors of float,
// but NOT HIP's float4 (a HIP_vector_type class) — that was R2's compile fail.
typedef float v4f __attribute__((ext_vector_type(4)));

// Single fused kernel, one block per row, no workspace.
//
// Layout probe (bool/1B vs int32/4B for where_input), done per block against
// the first 256 bytes (L2-hot): in an int32 {0,1} buffer every byte at
// p%4!=0 is zero; in a bool buffer ~96/192 such bytes are nonzero. R1 passed
// absmax=0 with this same two-way detection, so layout is one of these two.
__global__ __launch_bounds__(256) void fused_slice_where_cat_kernel(
    const unsigned char* __restrict__ w,   // where_input, layout probed
    const v4f* __restrict__ slice_in,      // B x 4096 v4f
    const v4f* __restrict__ unmatched,     // B x 64 v4f
    v4f* __restrict__ out) {               // B x 2112 v4f
  const int b = blockIdx.x;
  const int t = threadIdx.x;

  __shared__ int s_bool_layout;
  if (t == 0) s_bool_layout = 0;
  __syncthreads();
  if ((t & 3) != 0 && w[t] != 0) s_bool_layout = 1;  // benign same-value race

  // Overlap the probe with the unmatched copy (first 64 threads, one wave).
  v4f* out_row = out + (size_t)b * OUT_F4;
  if (t < UN_F4) {
    v4f u = __builtin_nontemporal_load(&unmatched[(size_t)b * UN_F4 + t]);
    __builtin_nontemporal_store(u, &out_row[t]);
  }
  __syncthreads();

  const int m = s_bool_layout ? (int)w[b] : ((const int*)w)[b];

  v4f* og = out_row + UN_F4;
  if (m != 0) {
    const v4f* src = slice_in + (size_t)b * SLICE_F4;
#pragma unroll
    for (int i = 0; i < 8; ++i) {
      const int v = t + i * 256;  // [0, 2048)
      // chunk s = v/32 (32 v4f = 128 f32 per chunk), chunk stride 64 v4f
      v4f x = __builtin_nontemporal_load(&src[((v >> 5) << 6) + (v & 31)]);
      __builtin_nontemporal_store(x, &og[v]);
    }
  } else {
    const v4f z = {0.f, 0.f, 0.f, 0.f};
#pragma unroll
    for (int i = 0; i < 8; ++i) {
      __builtin_nontemporal_store(z, &og[t + i * 256]);
    }
  }
}

extern "C" void kernel_launch(void* const* d_in, const int* in_sizes, int n_in,
                              void* d_out, int out_size, void* d_ws, size_t ws_size,
                              hipStream_t stream) {
  // setup_inputs order: where_input (B), slice_input (B*16384), unmatched
  // (B*256), cat_dim (1), slice_dim (1). Output: B*8448 f32.
  const unsigned char* d_where = (const unsigned char*)d_in[0];
  const v4f* d_slice = (const v4f*)d_in[1];
  const v4f* d_un    = (const v4f*)d_in[2];
  v4f* out = (v4f*)d_out;
  fused_slice_where_cat_kernel<<<B, 256, 0, stream>>>(d_where, d_slice, d_un, out);
}